// Round 17
// baseline (264.905 us; speedup 1.0000x reference)
//
#include <hip/hip_runtime.h>
#include <hip/hip_fp16.h>
#include <math.h>

// ---------------------------------------------------------------------------
// SGConv (K=2) + linear + relu + linear + sigmoid.
// N = 500K nodes (dim 1), E = 16M random edges, self-loops w=1.
//
// Destination-bucketed edge partition (BSZ=8192, nb=62), accumulation in LDS
// with i32 FIXED-POINT atomics (exact, order-independent). 6 B/edge split
// streams (u32 packed idx + fp16 w), packed-u32 w16 flush.
// Round 17: stage w as FULL u32 LDS words (word-aligned place/flush reads,
// no sub-word LDS writes) to claw back the R16 scatter VALU regression.
//   h[c] = dinv[c] * ( sum_e w*g[row] + g[c] ),  g = dinv .* h_prev
// ---------------------------------------------------------------------------

#define BSH  13
#define BSZ  8192      // nodes per bucket (13 bits local + 19 bits row = 32)
#define MAXB 64        // max buckets
#define NBLK 512       // partition blocks
#define SCT  1024      // threads in count/scatter
#define PR   (4*SCT)   // edges per scatter round
#define ACT  1024      // threads in accum
#define SD   144       // staging depth per bucket
#define SDI  145       // idx stage stride (u32)
#define SDW  145       // w stage stride (u32 words)
#define EPAD (64*MAXB) // bucket-base padding allowance

#define FIX_SCALE     1048576.0f          // 2^20
#define FIX_INV_SCALE (1.0f/1048576.0f)

// ---------- partition passes ----------

__global__ void k_count(const int* __restrict__ col, int E, int chunk,
                        unsigned* __restrict__ cnt, int nb, int vec_ok) {
    __shared__ unsigned hist[MAXB];
    const int k = blockIdx.x;
    for (int i = threadIdx.x; i < nb; i += blockDim.x) hist[i] = 0;
    __syncthreads();
    const int lo = k * chunk;
    const int hi = min(E, lo + chunk);
    const int len = hi - lo;
    if (len > 0) {
        if (vec_ok) {
            const int nv = len >> 2;
            const uint4* c4 = (const uint4*)(col + lo);
            for (int i = threadIdx.x; i < nv; i += blockDim.x) {
                uint4 v = c4[i];
                atomicAdd(&hist[v.x >> BSH], 1u);
                atomicAdd(&hist[v.y >> BSH], 1u);
                atomicAdd(&hist[v.z >> BSH], 1u);
                atomicAdd(&hist[v.w >> BSH], 1u);
            }
            for (int i = lo + (nv << 2) + (int)threadIdx.x; i < hi; i += blockDim.x)
                atomicAdd(&hist[((unsigned)col[i]) >> BSH], 1u);
        } else {
            for (int i = lo + (int)threadIdx.x; i < hi; i += blockDim.x)
                atomicAdd(&hist[((unsigned)col[i]) >> BSH], 1u);
        }
    }
    __syncthreads();
    for (int i = threadIdx.x; i < nb; i += blockDim.x)
        cnt[(size_t)i * NBLK + k] = hist[i];        // bucket-major
}

// block b: exclusive scan of cnt[b][0..NBLK) -> off[b][*]; total -> gtot[b]
__global__ void k_scan_bucket(const unsigned* __restrict__ cnt,
                              unsigned* __restrict__ off,
                              unsigned* __restrict__ gtot) {
    __shared__ unsigned sc[128];
    const int b = blockIdx.x, t = threadIdx.x;      // 128 threads, NBLK=512
    const uint4* src = (const uint4*)(cnt + (size_t)b * NBLK);
    uint4 v = src[t];
    unsigned s = v.x + v.y + v.z + v.w;
    sc[t] = s; __syncthreads();
    #pragma unroll
    for (int d = 1; d < 128; d <<= 1) {
        unsigned a = (t >= d) ? sc[t - d] : 0;
        __syncthreads();
        sc[t] += a;
        __syncthreads();
    }
    unsigned run = sc[t] - s;                       // exclusive prefix
    uint4 o;
    o.x = run; run += v.x;
    o.y = run; run += v.y;
    o.z = run; run += v.z;
    o.w = run;
    ((uint4*)(off + (size_t)b * NBLK))[t] = o;
    if (t == 127) gtot[b] = sc[127];
}

// bucket bases padded to multiples of 64 edges (keeps idx 16B / w16 8B aligned)
__global__ void k_scan_base(const unsigned* __restrict__ gtot,
                            unsigned* __restrict__ bstart, int nb) {
    __shared__ unsigned sc[64];
    const int t = threadIdx.x;                      // 64 threads
    unsigned s = (t < nb) ? ((gtot[t] + 63u) & ~63u) : 0;
    sc[t] = s; __syncthreads();
    #pragma unroll
    for (int d = 1; d < 64; d <<= 1) {
        unsigned a = (t >= d) ? sc[t - d] : 0;
        __syncthreads();
        sc[t] += a;
        __syncthreads();
    }
    if (t < nb) bstart[t] = sc[t] - s;
    if (t == 0) bstart[nb] = sc[63];
}

// LDS-staged scatter: 4 edges/thread/round, register prefetch across barriers,
// split output streams (u32 idx + fp16 w), w staged as full u32 words.
__global__ __launch_bounds__(SCT, 2)
void k_scatter(const int* __restrict__ row, const int* __restrict__ col,
               const float* __restrict__ w, int E, int chunk,
               const unsigned* __restrict__ off,
               const unsigned* __restrict__ bstart, int nb,
               unsigned* __restrict__ idxs, unsigned short* __restrict__ w16g,
               int vec_ok) {
    __shared__ unsigned sidx[MAXB][SDI];
    __shared__ unsigned sw[MAXB][SDW];     // one u32 word per staged edge
    __shared__ unsigned fill[MAXB];
    __shared__ unsigned gbase[MAXB];
    const int k = blockIdx.x;
    const int tid = threadIdx.x;
    for (int i = tid; i < nb; i += blockDim.x) {
        fill[i]  = 0;
        gbase[i] = bstart[i] + off[(size_t)i * NBLK + k];
    }
    __syncthreads();
    const int lo = k * chunk;
    const int hi = min(E, lo + chunk);
    const int wv = tid >> 6, ln = tid & 63;
    const int nwv = SCT >> 6;

    auto place = [&](unsigned c, unsigned r, float ww) {
        unsigned b = c >> BSH;
        unsigned pk = (c & (BSZ - 1)) | (r << BSH);
        unsigned hw = (unsigned)__half_as_ushort(__float2half(ww));
        unsigned p = atomicAdd(&fill[b], 1u);
        if (p < SD) { sidx[b][p] = pk; sw[b][p] = hw; }
        else {                                       // rare overflow, still exact
            unsigned gp = gbase[b] + p;
            idxs[gp] = pk; w16g[gp] = (unsigned short)hw;
        }
    };

    // preload round 0
    uint4 c4, r4; float4 w4;
    int idx0 = lo + tid * 4;
    int have = hi - idx0; have = have < 0 ? 0 : (have > 4 ? 4 : have);
    bool quad = (have == 4) && vec_ok;
    if (quad) {
        c4 = *(const uint4*)(col + idx0);
        r4 = *(const uint4*)(row + idx0);
        w4 = *(const float4*)(w + idx0);
    }

    for (int base = lo; base < hi; base += PR) {
        const int idx = base + tid * 4;
        if (quad) {
            place(c4.x, r4.x, w4.x);
            place(c4.y, r4.y, w4.y);
            place(c4.z, r4.z, w4.z);
            place(c4.w, r4.w, w4.w);
        } else {
            for (int j = 0; j < have; ++j) {
                place((unsigned)col[idx + j], (unsigned)row[idx + j], w[idx + j]);
            }
        }
        // prefetch next round into registers (survives the barriers)
        const int idxn = base + PR + tid * 4;
        int hn = hi - idxn; hn = hn < 0 ? 0 : (hn > 4 ? 4 : hn);
        const bool quadn = (hn == 4) && vec_ok;
        uint4 nc4, nr4; float4 nw4;
        if (quadn) {
            nc4 = *(const uint4*)(col + idxn);
            nr4 = *(const uint4*)(row + idxn);
            nw4 = *(const float4*)(w + idxn);
        }
        __syncthreads();
        // flush: wave wv owns buckets wv, wv+nwv, ...
        for (int b = wv; b < nb; b += nwv) {
            unsigned nf  = fill[b];
            unsigned nfl = nf < SD ? nf : SD;
            unsigned gb  = gbase[b];
            // idx stream: plain u32 run
            for (unsigned l = (unsigned)ln; l < nfl; l += 64u)
                idxs[gb + l] = sidx[b][l];
            // w16 stream: packed u32 interior words + <=2 boundary 2B stores
            if (nfl) {
                unsigned wlo = (gb + 1u) >> 1;
                unsigned whi = (gb + nfl) >> 1;
                unsigned* w32 = (unsigned*)w16g;
                for (unsigned wi = wlo + (unsigned)ln; wi < whi; wi += 64u) {
                    unsigned s0 = (wi << 1) - gb;
                    unsigned pk = sw[b][s0] | (sw[b][s0 + 1] << 16);
                    w32[wi] = pk;
                }
                if (ln == 0) {
                    if (gb & 1u)          w16g[gb] = (unsigned short)sw[b][0];
                    if ((gb + nfl) & 1u)  w16g[gb + nfl - 1] =
                                              (unsigned short)sw[b][nfl - 1];
                }
            }
            if (ln == 0) { gbase[b] = gb + nf; fill[b] = 0; }
        }
        __syncthreads();
        c4 = nc4; r4 = nr4; w4 = nw4; have = hn; quad = quadn;
    }
}

// ---------- bucketed accumulation (i32 fixed-point, 2-deep pipeline) --------
// 4 edges per iter-unit: uint4 idx (16B) + uint2 of 4 halfs (8B)

template <bool GATHER>
__device__ __forceinline__
void accum_body(int* acc,
                const unsigned* __restrict__ idxs,
                const unsigned short* __restrict__ w16g,
                const unsigned* __restrict__ bstart,
                const unsigned* __restrict__ gtot,
                const float* __restrict__ gin,
                float* __restrict__ partials, int S, int nb) {
    const int bid = blockIdx.x;
    const int b = bid / S, s = bid - b * S;
    const int tid = threadIdx.x;
    for (int i = tid; i < BSZ; i += ACT) acc[i] = 0;
    __syncthreads();
    const unsigned lo  = bstart[b];
    const unsigned len = gtot[b];
    unsigned s0 = (unsigned)(((unsigned long long)len * s) / S);
    unsigned s1 = (s == S - 1) ? len
                               : (unsigned)(((unsigned long long)len * (s + 1)) / S);
    s0 = (s0 + 3u) & ~3u; if (s0 > len) s0 = len;
    if (s != S - 1) { s1 = (s1 + 3u) & ~3u; if (s1 > len) s1 = len; }
    const unsigned start = lo + s0;
    const unsigned diff  = (s1 > s0) ? (s1 - s0) : 0;
    const unsigned nu    = diff >> 2;               // units of 4 edges
    const uint4* i4 = (const uint4*)(idxs + start);
    const uint2* h4 = (const uint2*)(w16g + start); // 4 halfs

    auto wf = [](unsigned hh, int hi4) {
        return __half2float(__ushort_as_half(
            (unsigned short)(hi4 ? (hh >> 16) : (hh & 0xFFFFu))));
    };

    // 2-deep software pipeline: 2 units (8 edges, 8 gathers) in flight
    unsigned i = tid;
    uint4 cA, cB; uint2 hA, hB;
    float gA0 = 0.f, gA1 = 0.f, gA2 = 0.f, gA3 = 0.f;
    float gB0 = 0.f, gB1 = 0.f, gB2 = 0.f, gB3 = 0.f;
    bool okA = i < nu;
    bool okB = (i + ACT) < nu;
    if (okA) {
        cA = i4[i]; hA = h4[i];
        if (GATHER) { gA0 = gin[cA.x >> BSH]; gA1 = gin[cA.y >> BSH];
                      gA2 = gin[cA.z >> BSH]; gA3 = gin[cA.w >> BSH]; }
    }
    if (okB) {
        cB = i4[i + ACT]; hB = h4[i + ACT];
        if (GATHER) { gB0 = gin[cB.x >> BSH]; gB1 = gin[cB.y >> BSH];
                      gB2 = gin[cB.z >> BSH]; gB3 = gin[cB.w >> BSH]; }
    }
    while (okA) {
        const unsigned nx = i + 2 * ACT;
        const bool okN = nx < nu;
        uint4 cN; uint2 hN;
        float gN0 = 0.f, gN1 = 0.f, gN2 = 0.f, gN3 = 0.f;
        if (okN) {
            cN = i4[nx]; hN = h4[nx];
            if (GATHER) { gN0 = gin[cN.x >> BSH]; gN1 = gin[cN.y >> BSH];
                          gN2 = gin[cN.z >> BSH]; gN3 = gin[cN.w >> BSH]; }
        }
        float f0 = wf(hA.x, 0), f1 = wf(hA.x, 1);
        float f2 = wf(hA.y, 0), f3 = wf(hA.y, 1);
        if (GATHER) { f0 *= gA0; f1 *= gA1; f2 *= gA2; f3 *= gA3; }
        atomicAdd(&acc[cA.x & (BSZ - 1)], __float2int_rn(f0 * FIX_SCALE));
        atomicAdd(&acc[cA.y & (BSZ - 1)], __float2int_rn(f1 * FIX_SCALE));
        atomicAdd(&acc[cA.z & (BSZ - 1)], __float2int_rn(f2 * FIX_SCALE));
        atomicAdd(&acc[cA.w & (BSZ - 1)], __float2int_rn(f3 * FIX_SCALE));
        i += ACT;
        cA = cB; hA = hB; gA0 = gB0; gA1 = gB1; gA2 = gB2; gA3 = gB3; okA = okB;
        cB = cN; hB = hN; gB0 = gN0; gB1 = gN1; gB2 = gN2; gB3 = gN3; okB = okN;
    }
    // <=3 leftover edges
    for (unsigned t = start + (nu << 2) + tid; t < start + diff; t += ACT) {
        unsigned v = idxs[t];
        float f = __half2float(__ushort_as_half(w16g[t]));
        if (GATHER) f *= gin[v >> BSH];
        atomicAdd(&acc[v & (BSZ - 1)], __float2int_rn(f * FIX_SCALE));
    }
    __syncthreads();
    float4* p4 = (float4*)(partials + ((size_t)s * nb + b) * BSZ);
    const float4* a4 = (const float4*)acc;          // bit-preserving copy
    for (int i2 = tid; i2 < BSZ / 4; i2 += ACT) p4[i2] = a4[i2];
}

__global__ __launch_bounds__(ACT)
void k_deg(const unsigned* __restrict__ idxs, const unsigned short* __restrict__ w16g,
           const unsigned* __restrict__ bstart, const unsigned* __restrict__ gtot,
           const float* __restrict__ gin, float* __restrict__ partials,
           int S, int nb) {
    __shared__ int acc[BSZ];
    accum_body<false>(acc, idxs, w16g, bstart, gtot, gin, partials, S, nb);
}

__global__ __launch_bounds__(ACT)
void k_hop1(const unsigned* __restrict__ idxs, const unsigned short* __restrict__ w16g,
            const unsigned* __restrict__ bstart, const unsigned* __restrict__ gtot,
            const float* __restrict__ gin, float* __restrict__ partials,
            int S, int nb) {
    __shared__ int acc[BSZ];
    accum_body<true>(acc, idxs, w16g, bstart, gtot, gin, partials, S, nb);
}

__global__ __launch_bounds__(ACT)
void k_hop2(const unsigned* __restrict__ idxs, const unsigned short* __restrict__ w16g,
            const unsigned* __restrict__ bstart, const unsigned* __restrict__ gtot,
            const float* __restrict__ gin, float* __restrict__ partials,
            int S, int nb) {
    __shared__ int acc[BSZ];
    accum_body<true>(acc, idxs, w16g, bstart, gtot, gin, partials, S, nb);
}

// mode 0: dinv = rsqrt(1+sum); gA = dinv*x
// mode 1: gB = dinv^2 * (sum + gA)
// mode 2: out = sigmoid(lin2(relu(lin1(dinv*(sum+gB)))))
__global__ void k_finish(int mode, const float* __restrict__ partials,
                         int S, int nb, int N,
                         const float* __restrict__ x,
                         float* __restrict__ dinv,
                         float* __restrict__ gA, float* __restrict__ gB,
                         float* __restrict__ out,
                         const float* __restrict__ cw, const float* __restrict__ cb,
                         const float* __restrict__ lw, const float* __restrict__ lb) {
    const int n = blockIdx.x * blockDim.x + threadIdx.x;
    if (n >= N) return;
    const int b = n >> BSH, i = n & (BSZ - 1);
    int is = 0;
    for (int s = 0; s < S; ++s)
        is += __float_as_int(partials[((size_t)s * nb + b) * BSZ + i]);
    float ssum = (float)is * FIX_INV_SCALE;
    if (mode == 0) {
        float di = rsqrtf(1.0f + ssum);             // deg >= 1 (self loop)
        dinv[n] = di;
        gA[n] = di * x[n];
    } else if (mode == 1) {
        float di = dinv[n];
        gB[n] = di * di * (ssum + gA[n]);
    } else {
        float di = dinv[n];
        float h2 = di * (ssum + gB[n]);
        float t = fmaxf(h2 * cw[0] + cb[0], 0.f);
        t = t * lw[0] + lb[0];
        out[n] = 1.f / (1.f + expf(-t));
    }
}

// ---------- fallback (round-1 proven atomic path) ----------

__global__ void k_init_deg(float* __restrict__ deg, int N) {
    int i = blockIdx.x * blockDim.x + threadIdx.x;
    if (i < N) deg[i] = 1.0f;
}
__global__ void k_scatter_deg(const int* __restrict__ col, const float* __restrict__ w,
                              float* __restrict__ deg, int E) {
    int stride = gridDim.x * blockDim.x;
    for (int e = blockIdx.x * blockDim.x + threadIdx.x; e < E; e += stride)
        atomicAdd(&deg[col[e]], w[e]);
}
__global__ void k_dinv_self(const float* __restrict__ x, float* __restrict__ deg_io,
                            float* __restrict__ h1, int N) {
    int i = blockIdx.x * blockDim.x + threadIdx.x;
    if (i >= N) return;
    float d = deg_io[i];
    float di = d > 0.0f ? rsqrtf(d) : 0.0f;
    deg_io[i] = di;
    h1[i] = di * di * x[i];
}
__global__ void k_self_seed(const float* __restrict__ src, const float* __restrict__ dinv,
                            float* __restrict__ dst, int N) {
    int i = blockIdx.x * blockDim.x + threadIdx.x;
    if (i >= N) return;
    float di = dinv[i];
    dst[i] = di * di * src[i];
}
__global__ void k_hop(const int* __restrict__ row, const int* __restrict__ col,
                      const float* __restrict__ w, const float* __restrict__ dinv,
                      const float* __restrict__ src, float* __restrict__ dst, int E) {
    int stride = gridDim.x * blockDim.x;
    for (int e = blockIdx.x * blockDim.x + threadIdx.x; e < E; e += stride) {
        int r = row[e], c = col[e];
        atomicAdd(&dst[c], dinv[r] * w[e] * dinv[c] * src[r]);
    }
}
__global__ void k_epilogue(float* __restrict__ io, const float* __restrict__ cw,
                           const float* __restrict__ cb, const float* __restrict__ lw,
                           const float* __restrict__ lb, int N) {
    int i = blockIdx.x * blockDim.x + threadIdx.x;
    if (i >= N) return;
    float h = fmaxf(io[i] * cw[0] + cb[0], 0.0f);
    h = h * lw[0] + lb[0];
    io[i] = 1.0f / (1.0f + expf(-h));
}

// ---------------------------------------------------------------------------

extern "C" void kernel_launch(void* const* d_in, const int* in_sizes, int n_in,
                              void* d_out, int out_size, void* d_ws, size_t ws_size,
                              hipStream_t stream) {
    const float* x  = (const float*)d_in[0];
    const int*   ei = (const int*)d_in[1];   // (2,E)
    const float* w  = (const float*)d_in[2];
    const float* cw = (const float*)d_in[3];
    const float* cb = (const float*)d_in[4];
    const float* lw = (const float*)d_in[5];
    const float* lb = (const float*)d_in[6];

    const int N = in_sizes[0];
    const int E = in_sizes[2];
    const int* row = ei;
    const int* col = ei + E;
    float* out = (float*)d_out;

    const int nb = (N + BSZ - 1) >> BSH;
    const size_t EC = (size_t)E + EPAD;      // padded edge capacity

    // --- choose config: S in {8,4,2,1}, first that fits ws; row needs 19 bits ---
    int S = 0;
    size_t o_bstart = 0, o_gtot = 0, o_dinv = 0, o_gA = 0, o_gB = 0,
           o_R = 0, o_idx = 0, o_w16 = 0;
    if (N <= (1 << 19) && nb >= 1 && nb <= MAXB) {
        for (int St : {8, 4, 2, 1}) {
            size_t o = 0;
            auto alloc = [&](size_t bytes) {
                o = (o + 255) & ~(size_t)255;
                size_t r = o; o += bytes; return r;
            };
            size_t b0 = alloc((size_t)(nb + 1) * 4);        // bstart
            size_t b1 = alloc((size_t)MAXB * 4);            // gtot
            size_t b2 = alloc((size_t)N * 4);               // dinv
            size_t b3 = alloc((size_t)N * 4);               // gA
            size_t b3b = alloc((size_t)N * 4);              // gB
            size_t cntoff = 2 * (size_t)NBLK * nb * 4;      // cnt + off
            size_t parts  = (size_t)St * nb * BSZ * 4;      // partials (aliased)
            size_t b4 = alloc(cntoff > parts ? cntoff : parts);
            size_t b5 = alloc(EC * 4);                      // idx stream
            size_t b6 = alloc(EC * 2);                      // w16 stream
            if (o <= ws_size) {
                S = St; o_bstart = b0; o_gtot = b1; o_dinv = b2;
                o_gA = b3; o_gB = b3b; o_R = b4; o_idx = b5; o_w16 = b6;
                break;
            }
        }
    }

    if (!S) {
        // ---- fallback: proven atomic path (needs 2N floats) ----
        float* dinv = (float*)d_ws;
        float* h1   = dinv + N;
        const int BT = 256;
        const int nbn = (N + BT - 1) / BT;
        int eb = (E + BT - 1) / BT; if (eb > 2048) eb = 2048;
        k_init_deg<<<nbn, BT, 0, stream>>>(dinv, N);
        k_scatter_deg<<<eb, BT, 0, stream>>>(col, w, dinv, E);
        k_dinv_self<<<nbn, BT, 0, stream>>>(x, dinv, h1, N);
        k_hop<<<eb, BT, 0, stream>>>(row, col, w, dinv, x, h1, E);
        k_self_seed<<<nbn, BT, 0, stream>>>(h1, dinv, out, N);
        k_hop<<<eb, BT, 0, stream>>>(row, col, w, dinv, h1, out, E);
        k_epilogue<<<nbn, BT, 0, stream>>>(out, cw, cb, lw, lb, N);
        return;
    }

    char* ws = (char*)d_ws;
    unsigned*       bstart   = (unsigned*)(ws + o_bstart);
    unsigned*       gtot     = (unsigned*)(ws + o_gtot);
    float*          dinv     = (float*)(ws + o_dinv);
    float*          gA       = (float*)(ws + o_gA);
    float*          gB       = (float*)(ws + o_gB);
    unsigned*       cnt      = (unsigned*)(ws + o_R);
    unsigned*       off      = cnt + (size_t)NBLK * nb;
    float*          partials = (float*)(ws + o_R);   // aliases cnt/off
    unsigned*       idxs     = (unsigned*)(ws + o_idx);
    unsigned short* w16g     = (unsigned short*)(ws + o_w16);

    int chunk = (E + NBLK - 1) / NBLK;
    chunk = (chunk + PR - 1) & ~(PR - 1);        // multiple of round size
    const int vec4_ok =
        ((((uintptr_t)col | (uintptr_t)row | (uintptr_t)w) & 15) == 0);

    const int fgrid = (N + 255) / 256;

    // partition
    k_count      <<<NBLK, SCT, 0, stream>>>(col, E, chunk, cnt, nb, vec4_ok);
    k_scan_bucket<<<nb,   128, 0, stream>>>(cnt, off, gtot);
    k_scan_base  <<<1,     64, 0, stream>>>(gtot, bstart, nb);
    k_scatter    <<<NBLK, SCT, 0, stream>>>(row, col, w, E, chunk, off, bstart, nb,
                                            idxs, w16g, vec4_ok);

    // accumulation passes (all i32 fixed-point, forward)
    k_deg <<<nb * S, ACT, 0, stream>>>(idxs, w16g, bstart, gtot,
                                       (const float*)nullptr, partials, S, nb);
    k_finish<<<fgrid, 256, 0, stream>>>(0, partials, S, nb, N, x, dinv, gA, gB,
                                        out, cw, cb, lw, lb);

    k_hop1<<<nb * S, ACT, 0, stream>>>(idxs, w16g, bstart, gtot, gA,
                                       partials, S, nb);
    k_finish<<<fgrid, 256, 0, stream>>>(1, partials, S, nb, N, x, dinv, gA, gB,
                                        out, cw, cb, lw, lb);

    k_hop2<<<nb * S, ACT, 0, stream>>>(idxs, w16g, bstart, gtot, gB,
                                       partials, S, nb);
    k_finish<<<fgrid, 256, 0, stream>>>(2, partials, S, nb, N, x, dinv, gA, gB,
                                        out, cw, cb, lw, lb);
}

// Round 18
// 262.882 us; speedup vs baseline: 1.0077x; 1.0077x over previous
//
#include <hip/hip_runtime.h>
#include <hip/hip_fp16.h>
#include <math.h>

// ---------------------------------------------------------------------------
// SGConv (K=2) + linear + relu + linear + sigmoid.
// N = 500K nodes (dim 1), E = 16M random edges, self-loops w=1.
//
// FINAL (= round-16 best-measured config, 263.2 us):
// Destination-bucketed edge partition (BSZ=8192, nb=62), accumulation in LDS
// with i32 FIXED-POINT atomics (exact, order-independent). 6 B/edge split
// streams (u32 packed idx + fp16 w), packed-u32 w16 flush (interior word
// stores + <=2 boundary 2B stores per run). LDS-staged scatter with register
// prefetch across flush barriers; count+scan for exact bucket offsets.
//   h[c] = dinv[c] * ( sum_e w*g[row] + g[c] ),  g = dinv .* h_prev
//
// Measured component budget (timed): count ~18, scans ~3, scatter ~91,
// 3 accum passes ~46 each (ds_add_u32 + L2-gather floor), finishes ~12.
// ---------------------------------------------------------------------------

#define BSH  13
#define BSZ  8192      // nodes per bucket (13 bits local + 19 bits row = 32)
#define MAXB 64        // max buckets
#define NBLK 512       // partition blocks
#define SCT  1024      // threads in count/scatter
#define PR   (4*SCT)   // edges per scatter round
#define ACT  1024      // threads in accum
#define SD   144       // staging depth per bucket
#define SDI  145       // idx stage stride (u32)
#define SDW  146       // w16 stage stride (ushort, even)
#define EPAD (64*MAXB) // bucket-base padding allowance

#define FIX_SCALE     1048576.0f          // 2^20
#define FIX_INV_SCALE (1.0f/1048576.0f)

// ---------- partition passes ----------

__global__ void k_count(const int* __restrict__ col, int E, int chunk,
                        unsigned* __restrict__ cnt, int nb, int vec_ok) {
    __shared__ unsigned hist[MAXB];
    const int k = blockIdx.x;
    for (int i = threadIdx.x; i < nb; i += blockDim.x) hist[i] = 0;
    __syncthreads();
    const int lo = k * chunk;
    const int hi = min(E, lo + chunk);
    const int len = hi - lo;
    if (len > 0) {
        if (vec_ok) {
            const int nv = len >> 2;
            const uint4* c4 = (const uint4*)(col + lo);
            for (int i = threadIdx.x; i < nv; i += blockDim.x) {
                uint4 v = c4[i];
                atomicAdd(&hist[v.x >> BSH], 1u);
                atomicAdd(&hist[v.y >> BSH], 1u);
                atomicAdd(&hist[v.z >> BSH], 1u);
                atomicAdd(&hist[v.w >> BSH], 1u);
            }
            for (int i = lo + (nv << 2) + (int)threadIdx.x; i < hi; i += blockDim.x)
                atomicAdd(&hist[((unsigned)col[i]) >> BSH], 1u);
        } else {
            for (int i = lo + (int)threadIdx.x; i < hi; i += blockDim.x)
                atomicAdd(&hist[((unsigned)col[i]) >> BSH], 1u);
        }
    }
    __syncthreads();
    for (int i = threadIdx.x; i < nb; i += blockDim.x)
        cnt[(size_t)i * NBLK + k] = hist[i];        // bucket-major
}

// block b: exclusive scan of cnt[b][0..NBLK) -> off[b][*]; total -> gtot[b]
__global__ void k_scan_bucket(const unsigned* __restrict__ cnt,
                              unsigned* __restrict__ off,
                              unsigned* __restrict__ gtot) {
    __shared__ unsigned sc[128];
    const int b = blockIdx.x, t = threadIdx.x;      // 128 threads, NBLK=512
    const uint4* src = (const uint4*)(cnt + (size_t)b * NBLK);
    uint4 v = src[t];
    unsigned s = v.x + v.y + v.z + v.w;
    sc[t] = s; __syncthreads();
    #pragma unroll
    for (int d = 1; d < 128; d <<= 1) {
        unsigned a = (t >= d) ? sc[t - d] : 0;
        __syncthreads();
        sc[t] += a;
        __syncthreads();
    }
    unsigned run = sc[t] - s;                       // exclusive prefix
    uint4 o;
    o.x = run; run += v.x;
    o.y = run; run += v.y;
    o.z = run; run += v.z;
    o.w = run;
    ((uint4*)(off + (size_t)b * NBLK))[t] = o;
    if (t == 127) gtot[b] = sc[127];
}

// bucket bases padded to multiples of 64 edges (keeps idx 16B / w16 8B aligned)
__global__ void k_scan_base(const unsigned* __restrict__ gtot,
                            unsigned* __restrict__ bstart, int nb) {
    __shared__ unsigned sc[64];
    const int t = threadIdx.x;                      // 64 threads
    unsigned s = (t < nb) ? ((gtot[t] + 63u) & ~63u) : 0;
    sc[t] = s; __syncthreads();
    #pragma unroll
    for (int d = 1; d < 64; d <<= 1) {
        unsigned a = (t >= d) ? sc[t - d] : 0;
        __syncthreads();
        sc[t] += a;
        __syncthreads();
    }
    if (t < nb) bstart[t] = sc[t] - s;
    if (t == 0) bstart[nb] = sc[63];
}

// LDS-staged scatter: 4 edges/thread/round, register prefetch across barriers,
// split output streams (u32 idx + fp16 w), packed-word w16 flush.
__global__ __launch_bounds__(SCT, 2)
void k_scatter(const int* __restrict__ row, const int* __restrict__ col,
               const float* __restrict__ w, int E, int chunk,
               const unsigned* __restrict__ off,
               const unsigned* __restrict__ bstart, int nb,
               unsigned* __restrict__ idxs, unsigned short* __restrict__ w16g,
               int vec_ok) {
    __shared__ unsigned       sidx[MAXB][SDI];
    __shared__ unsigned short sw[MAXB][SDW];
    __shared__ unsigned       fill[MAXB];
    __shared__ unsigned       gbase[MAXB];
    const int k = blockIdx.x;
    const int tid = threadIdx.x;
    for (int i = tid; i < nb; i += blockDim.x) {
        fill[i]  = 0;
        gbase[i] = bstart[i] + off[(size_t)i * NBLK + k];
    }
    __syncthreads();
    const int lo = k * chunk;
    const int hi = min(E, lo + chunk);
    const int wv = tid >> 6, ln = tid & 63;
    const int nwv = SCT >> 6;

    auto place = [&](unsigned c, unsigned r, float ww) {
        unsigned b = c >> BSH;
        unsigned pk = (c & (BSZ - 1)) | (r << BSH);
        unsigned short hw = __half_as_ushort(__float2half(ww));
        unsigned p = atomicAdd(&fill[b], 1u);
        if (p < SD) { sidx[b][p] = pk; sw[b][p] = hw; }
        else {                                       // rare overflow, still exact
            unsigned gp = gbase[b] + p;
            idxs[gp] = pk; w16g[gp] = hw;
        }
    };

    // preload round 0
    uint4 c4, r4; float4 w4;
    int idx0 = lo + tid * 4;
    int have = hi - idx0; have = have < 0 ? 0 : (have > 4 ? 4 : have);
    bool quad = (have == 4) && vec_ok;
    if (quad) {
        c4 = *(const uint4*)(col + idx0);
        r4 = *(const uint4*)(row + idx0);
        w4 = *(const float4*)(w + idx0);
    }

    for (int base = lo; base < hi; base += PR) {
        const int idx = base + tid * 4;
        if (quad) {
            place(c4.x, r4.x, w4.x);
            place(c4.y, r4.y, w4.y);
            place(c4.z, r4.z, w4.z);
            place(c4.w, r4.w, w4.w);
        } else {
            for (int j = 0; j < have; ++j) {
                place((unsigned)col[idx + j], (unsigned)row[idx + j], w[idx + j]);
            }
        }
        // prefetch next round into registers (survives the barriers)
        const int idxn = base + PR + tid * 4;
        int hn = hi - idxn; hn = hn < 0 ? 0 : (hn > 4 ? 4 : hn);
        const bool quadn = (hn == 4) && vec_ok;
        uint4 nc4, nr4; float4 nw4;
        if (quadn) {
            nc4 = *(const uint4*)(col + idxn);
            nr4 = *(const uint4*)(row + idxn);
            nw4 = *(const float4*)(w + idxn);
        }
        __syncthreads();
        // flush: wave wv owns buckets wv, wv+nwv, ...
        for (int b = wv; b < nb; b += nwv) {
            unsigned nf  = fill[b];
            unsigned nfl = nf < SD ? nf : SD;
            unsigned gb  = gbase[b];
            // idx stream: plain u32 run
            for (unsigned l = (unsigned)ln; l < nfl; l += 64u)
                idxs[gb + l] = sidx[b][l];
            // w16 stream: packed u32 interior words + <=2 boundary 2B stores
            if (nfl) {
                unsigned wlo = (gb + 1u) >> 1;
                unsigned whi = (gb + nfl) >> 1;
                unsigned* w32 = (unsigned*)w16g;
                for (unsigned wi = wlo + (unsigned)ln; wi < whi; wi += 64u) {
                    unsigned s0 = (wi << 1) - gb;
                    unsigned pk = (unsigned)sw[b][s0] |
                                  ((unsigned)sw[b][s0 + 1] << 16);
                    w32[wi] = pk;
                }
                if (ln == 0) {
                    if (gb & 1u)          w16g[gb] = sw[b][0];
                    if ((gb + nfl) & 1u)  w16g[gb + nfl - 1] = sw[b][nfl - 1];
                }
            }
            if (ln == 0) { gbase[b] = gb + nf; fill[b] = 0; }
        }
        __syncthreads();
        c4 = nc4; r4 = nr4; w4 = nw4; have = hn; quad = quadn;
    }
}

// ---------- bucketed accumulation (i32 fixed-point, 2-deep pipeline) --------
// 4 edges per iter-unit: uint4 idx (16B) + uint2 of 4 halfs (8B)

template <bool GATHER>
__device__ __forceinline__
void accum_body(int* acc,
                const unsigned* __restrict__ idxs,
                const unsigned short* __restrict__ w16g,
                const unsigned* __restrict__ bstart,
                const unsigned* __restrict__ gtot,
                const float* __restrict__ gin,
                float* __restrict__ partials, int S, int nb) {
    const int bid = blockIdx.x;
    const int b = bid / S, s = bid - b * S;
    const int tid = threadIdx.x;
    for (int i = tid; i < BSZ; i += ACT) acc[i] = 0;
    __syncthreads();
    const unsigned lo  = bstart[b];
    const unsigned len = gtot[b];
    unsigned s0 = (unsigned)(((unsigned long long)len * s) / S);
    unsigned s1 = (s == S - 1) ? len
                               : (unsigned)(((unsigned long long)len * (s + 1)) / S);
    s0 = (s0 + 3u) & ~3u; if (s0 > len) s0 = len;
    if (s != S - 1) { s1 = (s1 + 3u) & ~3u; if (s1 > len) s1 = len; }
    const unsigned start = lo + s0;
    const unsigned diff  = (s1 > s0) ? (s1 - s0) : 0;
    const unsigned nu    = diff >> 2;               // units of 4 edges
    const uint4* i4 = (const uint4*)(idxs + start);
    const uint2* h4 = (const uint2*)(w16g + start); // 4 halfs

    auto wf = [](unsigned hh, int hi4) {
        return __half2float(__ushort_as_half(
            (unsigned short)(hi4 ? (hh >> 16) : (hh & 0xFFFFu))));
    };

    // 2-deep software pipeline: 2 units (8 edges, 8 gathers) in flight
    unsigned i = tid;
    uint4 cA, cB; uint2 hA, hB;
    float gA0 = 0.f, gA1 = 0.f, gA2 = 0.f, gA3 = 0.f;
    float gB0 = 0.f, gB1 = 0.f, gB2 = 0.f, gB3 = 0.f;
    bool okA = i < nu;
    bool okB = (i + ACT) < nu;
    if (okA) {
        cA = i4[i]; hA = h4[i];
        if (GATHER) { gA0 = gin[cA.x >> BSH]; gA1 = gin[cA.y >> BSH];
                      gA2 = gin[cA.z >> BSH]; gA3 = gin[cA.w >> BSH]; }
    }
    if (okB) {
        cB = i4[i + ACT]; hB = h4[i + ACT];
        if (GATHER) { gB0 = gin[cB.x >> BSH]; gB1 = gin[cB.y >> BSH];
                      gB2 = gin[cB.z >> BSH]; gB3 = gin[cB.w >> BSH]; }
    }
    while (okA) {
        const unsigned nx = i + 2 * ACT;
        const bool okN = nx < nu;
        uint4 cN; uint2 hN;
        float gN0 = 0.f, gN1 = 0.f, gN2 = 0.f, gN3 = 0.f;
        if (okN) {
            cN = i4[nx]; hN = h4[nx];
            if (GATHER) { gN0 = gin[cN.x >> BSH]; gN1 = gin[cN.y >> BSH];
                          gN2 = gin[cN.z >> BSH]; gN3 = gin[cN.w >> BSH]; }
        }
        float f0 = wf(hA.x, 0), f1 = wf(hA.x, 1);
        float f2 = wf(hA.y, 0), f3 = wf(hA.y, 1);
        if (GATHER) { f0 *= gA0; f1 *= gA1; f2 *= gA2; f3 *= gA3; }
        atomicAdd(&acc[cA.x & (BSZ - 1)], __float2int_rn(f0 * FIX_SCALE));
        atomicAdd(&acc[cA.y & (BSZ - 1)], __float2int_rn(f1 * FIX_SCALE));
        atomicAdd(&acc[cA.z & (BSZ - 1)], __float2int_rn(f2 * FIX_SCALE));
        atomicAdd(&acc[cA.w & (BSZ - 1)], __float2int_rn(f3 * FIX_SCALE));
        i += ACT;
        cA = cB; hA = hB; gA0 = gB0; gA1 = gB1; gA2 = gB2; gA3 = gB3; okA = okB;
        cB = cN; hB = hN; gB0 = gN0; gB1 = gN1; gB2 = gN2; gB3 = gN3; okB = okN;
    }
    // <=3 leftover edges
    for (unsigned t = start + (nu << 2) + tid; t < start + diff; t += ACT) {
        unsigned v = idxs[t];
        float f = __half2float(__ushort_as_half(w16g[t]));
        if (GATHER) f *= gin[v >> BSH];
        atomicAdd(&acc[v & (BSZ - 1)], __float2int_rn(f * FIX_SCALE));
    }
    __syncthreads();
    float4* p4 = (float4*)(partials + ((size_t)s * nb + b) * BSZ);
    const float4* a4 = (const float4*)acc;          // bit-preserving copy
    for (int i2 = tid; i2 < BSZ / 4; i2 += ACT) p4[i2] = a4[i2];
}

__global__ __launch_bounds__(ACT)
void k_deg(const unsigned* __restrict__ idxs, const unsigned short* __restrict__ w16g,
           const unsigned* __restrict__ bstart, const unsigned* __restrict__ gtot,
           const float* __restrict__ gin, float* __restrict__ partials,
           int S, int nb) {
    __shared__ int acc[BSZ];
    accum_body<false>(acc, idxs, w16g, bstart, gtot, gin, partials, S, nb);
}

__global__ __launch_bounds__(ACT)
void k_hop1(const unsigned* __restrict__ idxs, const unsigned short* __restrict__ w16g,
            const unsigned* __restrict__ bstart, const unsigned* __restrict__ gtot,
            const float* __restrict__ gin, float* __restrict__ partials,
            int S, int nb) {
    __shared__ int acc[BSZ];
    accum_body<true>(acc, idxs, w16g, bstart, gtot, gin, partials, S, nb);
}

__global__ __launch_bounds__(ACT)
void k_hop2(const unsigned* __restrict__ idxs, const unsigned short* __restrict__ w16g,
            const unsigned* __restrict__ bstart, const unsigned* __restrict__ gtot,
            const float* __restrict__ gin, float* __restrict__ partials,
            int S, int nb) {
    __shared__ int acc[BSZ];
    accum_body<true>(acc, idxs, w16g, bstart, gtot, gin, partials, S, nb);
}

// mode 0: dinv = rsqrt(1+sum); gA = dinv*x
// mode 1: gB = dinv^2 * (sum + gA)
// mode 2: out = sigmoid(lin2(relu(lin1(dinv*(sum+gB)))))
__global__ void k_finish(int mode, const float* __restrict__ partials,
                         int S, int nb, int N,
                         const float* __restrict__ x,
                         float* __restrict__ dinv,
                         float* __restrict__ gA, float* __restrict__ gB,
                         float* __restrict__ out,
                         const float* __restrict__ cw, const float* __restrict__ cb,
                         const float* __restrict__ lw, const float* __restrict__ lb) {
    const int n = blockIdx.x * blockDim.x + threadIdx.x;
    if (n >= N) return;
    const int b = n >> BSH, i = n & (BSZ - 1);
    int is = 0;
    for (int s = 0; s < S; ++s)
        is += __float_as_int(partials[((size_t)s * nb + b) * BSZ + i]);
    float ssum = (float)is * FIX_INV_SCALE;
    if (mode == 0) {
        float di = rsqrtf(1.0f + ssum);             // deg >= 1 (self loop)
        dinv[n] = di;
        gA[n] = di * x[n];
    } else if (mode == 1) {
        float di = dinv[n];
        gB[n] = di * di * (ssum + gA[n]);
    } else {
        float di = dinv[n];
        float h2 = di * (ssum + gB[n]);
        float t = fmaxf(h2 * cw[0] + cb[0], 0.f);
        t = t * lw[0] + lb[0];
        out[n] = 1.f / (1.f + expf(-t));
    }
}

// ---------- fallback (round-1 proven atomic path) ----------

__global__ void k_init_deg(float* __restrict__ deg, int N) {
    int i = blockIdx.x * blockDim.x + threadIdx.x;
    if (i < N) deg[i] = 1.0f;
}
__global__ void k_scatter_deg(const int* __restrict__ col, const float* __restrict__ w,
                              float* __restrict__ deg, int E) {
    int stride = gridDim.x * blockDim.x;
    for (int e = blockIdx.x * blockDim.x + threadIdx.x; e < E; e += stride)
        atomicAdd(&deg[col[e]], w[e]);
}
__global__ void k_dinv_self(const float* __restrict__ x, float* __restrict__ deg_io,
                            float* __restrict__ h1, int N) {
    int i = blockIdx.x * blockDim.x + threadIdx.x;
    if (i >= N) return;
    float d = deg_io[i];
    float di = d > 0.0f ? rsqrtf(d) : 0.0f;
    deg_io[i] = di;
    h1[i] = di * di * x[i];
}
__global__ void k_self_seed(const float* __restrict__ src, const float* __restrict__ dinv,
                            float* __restrict__ dst, int N) {
    int i = blockIdx.x * blockDim.x + threadIdx.x;
    if (i >= N) return;
    float di = dinv[i];
    dst[i] = di * di * src[i];
}
__global__ void k_hop(const int* __restrict__ row, const int* __restrict__ col,
                      const float* __restrict__ w, const float* __restrict__ dinv,
                      const float* __restrict__ src, float* __restrict__ dst, int E) {
    int stride = gridDim.x * blockDim.x;
    for (int e = blockIdx.x * blockDim.x + threadIdx.x; e < E; e += stride) {
        int r = row[e], c = col[e];
        atomicAdd(&dst[c], dinv[r] * w[e] * dinv[c] * src[r]);
    }
}
__global__ void k_epilogue(float* __restrict__ io, const float* __restrict__ cw,
                           const float* __restrict__ cb, const float* __restrict__ lw,
                           const float* __restrict__ lb, int N) {
    int i = blockIdx.x * blockDim.x + threadIdx.x;
    if (i >= N) return;
    float h = fmaxf(io[i] * cw[0] + cb[0], 0.0f);
    h = h * lw[0] + lb[0];
    io[i] = 1.0f / (1.0f + expf(-h));
}

// ---------------------------------------------------------------------------

extern "C" void kernel_launch(void* const* d_in, const int* in_sizes, int n_in,
                              void* d_out, int out_size, void* d_ws, size_t ws_size,
                              hipStream_t stream) {
    const float* x  = (const float*)d_in[0];
    const int*   ei = (const int*)d_in[1];   // (2,E)
    const float* w  = (const float*)d_in[2];
    const float* cw = (const float*)d_in[3];
    const float* cb = (const float*)d_in[4];
    const float* lw = (const float*)d_in[5];
    const float* lb = (const float*)d_in[6];

    const int N = in_sizes[0];
    const int E = in_sizes[2];
    const int* row = ei;
    const int* col = ei + E;
    float* out = (float*)d_out;

    const int nb = (N + BSZ - 1) >> BSH;
    const size_t EC = (size_t)E + EPAD;      // padded edge capacity

    // --- choose config: S in {8,4,2,1}, first that fits ws; row needs 19 bits ---
    int S = 0;
    size_t o_bstart = 0, o_gtot = 0, o_dinv = 0, o_gA = 0, o_gB = 0,
           o_R = 0, o_idx = 0, o_w16 = 0;
    if (N <= (1 << 19) && nb >= 1 && nb <= MAXB) {
        for (int St : {8, 4, 2, 1}) {
            size_t o = 0;
            auto alloc = [&](size_t bytes) {
                o = (o + 255) & ~(size_t)255;
                size_t r = o; o += bytes; return r;
            };
            size_t b0 = alloc((size_t)(nb + 1) * 4);        // bstart
            size_t b1 = alloc((size_t)MAXB * 4);            // gtot
            size_t b2 = alloc((size_t)N * 4);               // dinv
            size_t b3 = alloc((size_t)N * 4);               // gA
            size_t b3b = alloc((size_t)N * 4);              // gB
            size_t cntoff = 2 * (size_t)NBLK * nb * 4;      // cnt + off
            size_t parts  = (size_t)St * nb * BSZ * 4;      // partials (aliased)
            size_t b4 = alloc(cntoff > parts ? cntoff : parts);
            size_t b5 = alloc(EC * 4);                      // idx stream
            size_t b6 = alloc(EC * 2);                      // w16 stream
            if (o <= ws_size) {
                S = St; o_bstart = b0; o_gtot = b1; o_dinv = b2;
                o_gA = b3; o_gB = b3b; o_R = b4; o_idx = b5; o_w16 = b6;
                break;
            }
        }
    }

    if (!S) {
        // ---- fallback: proven atomic path (needs 2N floats) ----
        float* dinv = (float*)d_ws;
        float* h1   = dinv + N;
        const int BT = 256;
        const int nbn = (N + BT - 1) / BT;
        int eb = (E + BT - 1) / BT; if (eb > 2048) eb = 2048;
        k_init_deg<<<nbn, BT, 0, stream>>>(dinv, N);
        k_scatter_deg<<<eb, BT, 0, stream>>>(col, w, dinv, E);
        k_dinv_self<<<nbn, BT, 0, stream>>>(x, dinv, h1, N);
        k_hop<<<eb, BT, 0, stream>>>(row, col, w, dinv, x, h1, E);
        k_self_seed<<<nbn, BT, 0, stream>>>(h1, dinv, out, N);
        k_hop<<<eb, BT, 0, stream>>>(row, col, w, dinv, h1, out, E);
        k_epilogue<<<nbn, BT, 0, stream>>>(out, cw, cb, lw, lb, N);
        return;
    }

    char* ws = (char*)d_ws;
    unsigned*       bstart   = (unsigned*)(ws + o_bstart);
    unsigned*       gtot     = (unsigned*)(ws + o_gtot);
    float*          dinv     = (float*)(ws + o_dinv);
    float*          gA       = (float*)(ws + o_gA);
    float*          gB       = (float*)(ws + o_gB);
    unsigned*       cnt      = (unsigned*)(ws + o_R);
    unsigned*       off      = cnt + (size_t)NBLK * nb;
    float*          partials = (float*)(ws + o_R);   // aliases cnt/off
    unsigned*       idxs     = (unsigned*)(ws + o_idx);
    unsigned short* w16g     = (unsigned short*)(ws + o_w16);

    int chunk = (E + NBLK - 1) / NBLK;
    chunk = (chunk + PR - 1) & ~(PR - 1);        // multiple of round size
    const int vec4_ok =
        ((((uintptr_t)col | (uintptr_t)row | (uintptr_t)w) & 15) == 0);

    const int fgrid = (N + 255) / 256;

    // partition
    k_count      <<<NBLK, SCT, 0, stream>>>(col, E, chunk, cnt, nb, vec4_ok);
    k_scan_bucket<<<nb,   128, 0, stream>>>(cnt, off, gtot);
    k_scan_base  <<<1,     64, 0, stream>>>(gtot, bstart, nb);
    k_scatter    <<<NBLK, SCT, 0, stream>>>(row, col, w, E, chunk, off, bstart, nb,
                                            idxs, w16g, vec4_ok);

    // accumulation passes (all i32 fixed-point, forward)
    k_deg <<<nb * S, ACT, 0, stream>>>(idxs, w16g, bstart, gtot,
                                       (const float*)nullptr, partials, S, nb);
    k_finish<<<fgrid, 256, 0, stream>>>(0, partials, S, nb, N, x, dinv, gA, gB,
                                        out, cw, cb, lw, lb);

    k_hop1<<<nb * S, ACT, 0, stream>>>(idxs, w16g, bstart, gtot, gA,
                                       partials, S, nb);
    k_finish<<<fgrid, 256, 0, stream>>>(1, partials, S, nb, N, x, dinv, gA, gB,
                                        out, cw, cb, lw, lb);

    k_hop2<<<nb * S, ACT, 0, stream>>>(idxs, w16g, bstart, gtot, gB,
                                       partials, S, nb);
    k_finish<<<fgrid, 256, 0, stream>>>(2, partials, S, nb, N, x, dinv, gA, gB,
                                        out, cw, cb, lw, lb);
}